// Round 10
// baseline (427.664 us; speedup 1.0000x reference)
//
#include <hip/hip_runtime.h>
#include <cstdint>
#include <cstddef>

#define DFEAT 512
#define BM 128
#define BN 128
#define BK 32

typedef __attribute__((ext_vector_type(8))) short bf16x8;
typedef __attribute__((ext_vector_type(4))) float f32x4;

#define GLOBAL_AS __attribute__((address_space(1)))
#define LDS_AS __attribute__((address_space(3)))

// float -> bf16 round-to-nearest-even (finite inputs)
__device__ __forceinline__ unsigned short f2bf(float f) {
  unsigned u = __float_as_uint(f);
  u = u + 0x7fffu + ((u >> 16) & 1u);
  return (unsigned short)(u >> 16);
}

__device__ __forceinline__ float bf2f_lo(unsigned u) { return __uint_as_float(u << 16); }
__device__ __forceinline__ float bf2f_hi(unsigned u) { return __uint_as_float(u & 0xffff0000u); }

__device__ __forceinline__ void gl_lds16(const void* g, void* l) {
  __builtin_amdgcn_global_load_lds((const GLOBAL_AS unsigned int*)g,
                                   (LDS_AS unsigned int*)l, 16, 0, 0);
}

__device__ __forceinline__ void cast8(const float* __restrict__ X,
                                      unsigned short* __restrict__ Xb, int g) {
  const f32x4 a = __builtin_nontemporal_load(reinterpret_cast<const f32x4*>(X + (size_t)g * 8));
  const f32x4 c = __builtin_nontemporal_load(reinterpret_cast<const f32x4*>(X + (size_t)g * 8 + 4));
  uint4 o;
  o.x = (unsigned)f2bf(a[0]) | ((unsigned)f2bf(a[1]) << 16);
  o.y = (unsigned)f2bf(a[2]) | ((unsigned)f2bf(a[3]) << 16);
  o.z = (unsigned)f2bf(c[0]) | ((unsigned)f2bf(c[1]) << 16);
  o.w = (unsigned)f2bf(c[2]) | ((unsigned)f2bf(c[3]) << 16);
  *reinterpret_cast<uint4*>(Xb + (size_t)g * 8) = o;
}

// count (latency-bound atomics) STRIPED 1:2 with the FIRST HALF of the Xb cast
// (BW-bound); the second half rides in k_scancast. Striping keeps both roles
// co-resident (concatenated ranges phase-serialize; R6 measured sum-of-parts).
__global__ void k_countcast(const int* __restrict__ dst, int* __restrict__ deg8,
                            int E, int N,
                            const float* __restrict__ X, unsigned short* __restrict__ Xb,
                            int castA8) {
  const int b = blockIdx.x;
  const int m = b % 3;
  if (m == 2) {                      // count: per-XCD-privatized histogram slice b&7
    const int i = (b / 3) * 256 + threadIdx.x;
    if (i < E) {
      const int d = __builtin_nontemporal_load(dst + i);
      atomicAdd(&deg8[(size_t)(b & 7) * N + d], 1);
    }
    return;
  }
  const int g = ((b / 3) * 2 + m) * 256 + threadIdx.x;   // Xb cast, groups [0, castA8)
  if (g < castA8) cast8(X, Xb, g);
}

// Multi-block recompute-prefix scan (blocks < SB) co-launched with the SECOND
// half of the Xb cast (blocks >= SB): scan only occupies 49x1024 threads, so
// the cast soaks up the otherwise-idle CUs. Scan reads the 8 privatized
// slices directly, writes deg + rowStart/fillPos = exclusive scan (no +1:
// cw holds edges only; self-loop folded into k_aggregate).
__global__ __launch_bounds__(1024) void k_scancast(const int* __restrict__ deg8,
                                                   int* __restrict__ deg,
                                                   int* __restrict__ rowStart,
                                                   int* __restrict__ fillPos, int N,
                                                   const float* __restrict__ X,
                                                   unsigned short* __restrict__ Xb,
                                                   int castA8, int total8) {
  const int SB = (N + 1023) >> 10;
  const int t = threadIdx.x;
  if (blockIdx.x >= SB) {            // cast tail: groups [castA8, total8)
    const int g = castA8 + (blockIdx.x - SB) * 1024 + t;
    if (g < total8) cast8(X, Xb, g);
    return;
  }
  const int base = blockIdx.x * 1024;
  __shared__ int sm[1024];
  // 1) prefix base = sum_{i<base} deg[i], recomputed from slices (no block dep)
  int pre = 0;
  for (int i = t; i < base; i += 1024) {
    int s = 0;
#pragma unroll
    for (int x = 0; x < 8; ++x) s += deg8[(size_t)x * N + i];
    pre += s;
  }
  sm[t] = pre;
  __syncthreads();
  for (int d = 512; d > 0; d >>= 1) {
    if (t < d) sm[t] += sm[t + d];
    __syncthreads();
  }
  const int blockBase = sm[0];
  __syncthreads();
  // 2) block-local inclusive scan of v = deg[idx]
  const int idx = base + t;
  int v = 0;
  if (idx < N) {
#pragma unroll
    for (int x = 0; x < 8; ++x) v += deg8[(size_t)x * N + idx];
    deg[idx] = v;
  }
  sm[t] = v;
  __syncthreads();
  for (int d = 1; d < 1024; d <<= 1) {
    const int o = (t >= d) ? sm[t - d] : 0;
    __syncthreads();
    sm[t] += o;
    __syncthreads();
  }
  if (idx < N) {
    const int ex = blockBase + sm[t] - v;   // exclusive prefix
    rowStart[idx] = ex;
    fillPos[idx] = ex;
    if (idx == N - 1) rowStart[N] = ex + v;
  }
}

// CSR fill (atomic cursor scatter) STRIPED 3:1 with Wt transpose-cast.
// cw[pos] = { src, rsqrt(deg[src]+1) }.
__global__ void k_fillwt(const int* __restrict__ src, const int* __restrict__ dst,
                         int* __restrict__ fillPos, int2* __restrict__ cw,
                         const int* __restrict__ deg, int E,
                         const float* __restrict__ W, unsigned short* __restrict__ Wt) {
  const int b = blockIdx.x;
  const int m = b & 3;
  if (m == 3) {                      // Wt[n][k] = bf16(W[k][n]), coalesced read
    const int i = (b >> 2) * 256 + threadIdx.x;
    if (i < DFEAT * DFEAT) {
      const int k = i >> 9, n = i & 511;
      Wt[(size_t)n * DFEAT + k] = f2bf(W[i]);
    }
    return;
  }
  const int i = ((b >> 2) * 3 + m) * 256 + threadIdx.x;  // fill
  if (i < E) {
    const int d = dst[i], s = src[i];
    const int pos = atomicAdd(&fillPos[d], 1);
    int2 q; q.x = s; q.y = __float_as_int(rsqrtf((float)(deg[s] + 1)));
    cw[pos] = q;
  }
}

// Half-row gather batch: 8 independent nontemporal cw loads then 8 independent
// 512B half-row gathers (uint2/lane) in flight. TAIL clamps to e-1 /
// zero-weight (clamped loads are cache hits). xh already includes the
// half+lane offset; src stride = DFEAT.
template <bool TAIL>
__device__ __forceinline__ void agg8h(const unsigned short* __restrict__ xh,
                                      const int2* __restrict__ cw,
                                      int p, int e, float* acc) {
  unsigned long long q[8];
#pragma unroll
  for (int i = 0; i < 8; ++i) {
    int pi = p + i;
    if (TAIL) pi = (pi < e) ? pi : (e - 1);
    q[i] = __builtin_nontemporal_load(reinterpret_cast<const unsigned long long*>(cw + pi));
  }
  uint2 v[8];
#pragma unroll
  for (int i = 0; i < 8; ++i)
    v[i] = *reinterpret_cast<const uint2*>(xh + (size_t)(unsigned)q[i] * DFEAT);
#pragma unroll
  for (int i = 0; i < 8; ++i) {
    float w = __uint_as_float((unsigned)(q[i] >> 32));
    if (TAIL) w = (p + i < e) ? w : 0.0f;
    acc[0] = fmaf(w, bf2f_lo(v[i].x), acc[0]); acc[1] = fmaf(w, bf2f_hi(v[i].x), acc[1]);
    acc[2] = fmaf(w, bf2f_lo(v[i].y), acc[2]); acc[3] = fmaf(w, bf2f_hi(v[i].y), acc[3]);
  }
}

// FEATURE-SPLIT aggregation: XCDs 0-3 (blockIdx&7 < 4) process features
// [0,256) for all rows; XCDs 4-7 features [256,512). Each edge's gather is a
// 512B half-row (>= 128B line -> full line utilization, unlike R3's 64B
// slabs). Each XCD now touches ~25 MB of Xb instead of ~45 MB -> cross-XCD
// duplication fetch drops ~2x. Round-robin blockIdx->XCD is a perf heuristic
// only; correctness is mapping-independent. One wave per row-half; self-loop
// folded into init (acc = sc*X[row]h, coalesced); sc = rsqrt(edges+1).
__global__ __launch_bounds__(256) void k_aggregate(const unsigned short* __restrict__ Xb,
                                                   const int2* __restrict__ cw,
                                                   const int* __restrict__ rowStart,
                                                   unsigned short* __restrict__ Y, int N) {
  const int b7 = blockIdx.x & 7;
  const int half = b7 >> 2;                         // feature half
  const int rq = (blockIdx.x >> 3) * 4 + (b7 & 3);  // row-quad, bijective
  const int row = rq * 4 + (threadIdx.x >> 6);
  const int lane = threadIdx.x & 63;
  const unsigned short* xh = Xb + half * 256 + lane * 4;
  float acc[4] = {0.f, 0.f, 0.f, 0.f};
  if (row < N) {
    const int s = rowStart[row], e = rowStart[row + 1];   // e==s allowed (no edges)
    const float sc = rsqrtf((float)(e - s + 1));          // degree incl. self-loop
    const uint2 v0 = *reinterpret_cast<const uint2*>(xh + (size_t)row * DFEAT);
    acc[0] = sc * bf2f_lo(v0.x); acc[1] = sc * bf2f_hi(v0.x);
    acc[2] = sc * bf2f_lo(v0.y); acc[3] = sc * bf2f_hi(v0.y);
    int p = s;
    for (; p + 8 <= e; p += 8) agg8h<false>(xh, cw, p, e, acc);
    if (p < e) agg8h<true>(xh, cw, p, e, acc);
#pragma unroll
    for (int j = 0; j < 4; ++j) acc[j] *= sc;
  }
  uint2 o;
  o.x = (unsigned)f2bf(acc[0]) | ((unsigned)f2bf(acc[1]) << 16);
  o.y = (unsigned)f2bf(acc[2]) | ((unsigned)f2bf(acc[3]) << 16);
  *reinterpret_cast<uint2*>(Y + (size_t)row * DFEAT + half * 256 + lane * 4) = o;
}

// out[M x 512] = LeakyReLU( Y(bf16) @ W + b ). 128x128 tile, BK=32,
// global_load_lds width-16 staging, 4 waves x (64x64 via 4x4 mfma 16x16x32).
// 1D grid, n-fastest + bijective chunked XCD swizzle (m204 form: nwg%8 != 0).
__global__ __launch_bounds__(256) void k_gemm(const unsigned short* __restrict__ Y,
                                              const unsigned short* __restrict__ Wt,
                                              const float* __restrict__ bias,
                                              float* __restrict__ out, int M) {
  __shared__ unsigned short As[BM * BK];  // 8 KB
  __shared__ unsigned short Bs[BN * BK];  // 8 KB
  const int tid = threadIdx.x;
  const int lane = tid & 63;
  const int wave = tid >> 6;
  const int l16 = lane & 15;
  const int quad = lane >> 4;
  const int wm = (wave >> 1) * 64;
  const int wn = (wave & 1) * 64;

  // bijective chunked XCD swizzle (nwg = Mtiles*4 = 1564, q=195, r=4)
  const int nwg = gridDim.x;
  const int q8 = nwg >> 3, r8 = nwg & 7;
  const int xcd = blockIdx.x & 7, loc = blockIdx.x >> 3;
  const int wg = (xcd < r8 ? xcd * (q8 + 1) : r8 * (q8 + 1) + (xcd - r8) * q8) + loc;
  const int m0 = (wg >> 2) * BM;   // n fastest -> A-panel reuse across 4 consecutive wg
  const int n0 = (wg & 3) * BN;

  f32x4 acc[4][4];
#pragma unroll
  for (int mi = 0; mi < 4; ++mi)
#pragma unroll
    for (int ni = 0; ni < 4; ++ni) { f32x4 z = {0.f, 0.f, 0.f, 0.f}; acc[mi][ni] = z; }

  // staging: LDS slot ci (16B units) holds global chunk (row=ci>>2, kq=((ci&3)-(row>>1))&3)
  const int ci0 = wave * 64 + lane;
  const int ci1 = 256 + ci0;
  const int ra0 = ci0 >> 2, ka0 = (((ci0 & 3) - (ra0 >> 1)) & 3) * 8;
  const int ra1 = ci1 >> 2, ka1 = (((ci1 & 3) - (ra1 >> 1)) & 3) * 8;

  const unsigned short* Ag0 = Y + (size_t)(m0 + ra0) * DFEAT + ka0;
  const unsigned short* Ag1 = Y + (size_t)(m0 + ra1) * DFEAT + ka1;
  const unsigned short* Bg0 = Wt + (size_t)(n0 + ra0) * DFEAT + ka0;
  const unsigned short* Bg1 = Wt + (size_t)(n0 + ra1) * DFEAT + ka1;
  unsigned short* La0 = As + ci0 * 8;
  unsigned short* La1 = As + ci1 * 8;
  unsigned short* Lb0 = Bs + ci0 * 8;
  unsigned short* Lb1 = Bs + ci1 * 8;

  // read side: fragment (row, kq=quad) lives at slot row*4 + ((quad + (row>>1)) & 3)
  const int rotA = (quad + ((wm + l16) >> 1)) & 3;   // same for all mi (16*mi/2 % 4 == 0)
  const int rotB = (quad + ((wn + l16) >> 1)) & 3;
  const unsigned short* AsRd = As + (wm + l16) * BK + rotA * 8;
  const unsigned short* BsRd = Bs + (wn + l16) * BK + rotB * 8;

  for (int kk = 0; kk < DFEAT; kk += BK) {
    gl_lds16(Ag0 + kk, La0);
    gl_lds16(Ag1 + kk, La1);
    gl_lds16(Bg0 + kk, Lb0);
    gl_lds16(Bg1 + kk, Lb1);
    __syncthreads();  // drains vmcnt (global_load_lds) per m97 semantics
    bf16x8 av[4], bv[4];
#pragma unroll
    for (int mi = 0; mi < 4; ++mi)
      av[mi] = *reinterpret_cast<const bf16x8*>(AsRd + mi * 16 * BK);
#pragma unroll
    for (int ni = 0; ni < 4; ++ni)
      bv[ni] = *reinterpret_cast<const bf16x8*>(BsRd + ni * 16 * BK);
#pragma unroll
    for (int mi = 0; mi < 4; ++mi)
#pragma unroll
      for (int ni = 0; ni < 4; ++ni)
        acc[mi][ni] = __builtin_amdgcn_mfma_f32_16x16x32_bf16(av[mi], bv[ni], acc[mi][ni], 0, 0, 0);
    __syncthreads();  // protect LDS before next stage
  }

  float bvals[4];
#pragma unroll
  for (int ni = 0; ni < 4; ++ni) bvals[ni] = bias[n0 + wn + 16 * ni + l16];

  // C/D layout: col = lane&15, row = quad*4 + r
#pragma unroll
  for (int mi = 0; mi < 4; ++mi) {
#pragma unroll
    for (int r = 0; r < 4; ++r) {
      int row = m0 + wm + 16 * mi + quad * 4 + r;
      if (row < M) {
#pragma unroll
        for (int ni = 0; ni < 4; ++ni) {
          float v = acc[mi][ni][r] + bvals[ni];
          v = (v >= 0.f) ? v : 0.01f * v;
          out[(size_t)row * DFEAT + n0 + wn + 16 * ni + l16] = v;
        }
      }
    }
  }
}

extern "C" void kernel_launch(void* const* d_in, const int* in_sizes, int n_in,
                              void* d_out, int out_size, void* d_ws, size_t ws_size,
                              hipStream_t stream) {
  const float* X = (const float*)d_in[0];
  const float* W = (const float*)d_in[1];
  const float* b = (const float*)d_in[2];
  const int* ei  = (const int*)d_in[3];
  const int D = DFEAT;
  const int N = in_sizes[0] / D;   // 50000
  const int E = in_sizes[3] / 2;   // 800000
  const int* src = ei;
  const int* dst = ei + E;
  float* out = (float*)d_out;

  // carve workspace (256B-aligned slices)
  uintptr_t p = (uintptr_t)d_ws;
  auto carve = [&](size_t bytes) -> void* {
    uintptr_t r = p;
    p += (bytes + 255) & ~(size_t)255;
    return (void*)r;
  };
  int*   deg8     = (int*)carve(sizeof(int) * (size_t)N * 8);
  int*   deg      = (int*)carve(sizeof(int) * (size_t)N);
  int*   rowStart = (int*)carve(sizeof(int) * (size_t)(N + 1));
  int*   fillPos  = (int*)carve(sizeof(int) * (size_t)N);
  int2*  cw       = (int2*)carve(sizeof(int2) * (size_t)E);
  unsigned short* Wt = (unsigned short*)carve(sizeof(unsigned short) * (size_t)D * D);
  const int Mtiles = (N + BM - 1) / BM;     // 391
  const int Mpad = Mtiles * BM;             // 50048 (div by 16: rq mapping needs Mpad%16==0)
  unsigned short* Y  = (unsigned short*)carve(sizeof(unsigned short) * (size_t)Mpad * D);

  // Xb (bf16 X) lives in d_out: 51.2 MB needed, 102.4 MB available; dead before k_gemm writes.
  unsigned short* Xb = (unsigned short*)d_out;

  const int total8 = N * D / 8;             // 3.2M 8-elem cast groups
  const int cb = (E + 255) / 256;           // 3125 count blocks
  const int castA8 = ((total8 / 2) + 255) & ~255;   // first-half cast groups (1.6M)
  const int castAb = castA8 / 256;          // 6250 cast blocks in A
  const int nA = 3 * (cb > (castAb + 1) / 2 ? cb : (castAb + 1) / 2);
  const int SB = (N + 1023) / 1024;         // 49 scan blocks
  const int nBcast = (total8 - castA8 + 1023) / 1024;
  const int fb = cb;
  const int fq = (fb + 2) / 3;
  const int wb = (D * D + 255) / 256;       // 1024 Wt blocks
  const int nC = 4 * (fq > wb ? fq : wb);

  hipMemsetAsync(deg8, 0, sizeof(int) * (size_t)N * 8, stream);
  hipLaunchKernelGGL(k_countcast, dim3(nA), dim3(256), 0, stream,
                     dst, deg8, E, N, X, Xb, castA8);
  hipLaunchKernelGGL(k_scancast,  dim3(SB + nBcast), dim3(1024), 0, stream,
                     deg8, deg, rowStart, fillPos, N, X, Xb, castA8, total8);
  hipLaunchKernelGGL(k_fillwt,    dim3(nC), dim3(256), 0, stream,
                     src, dst, fillPos, cw, deg, E, W, Wt);
  hipLaunchKernelGGL(k_aggregate, dim3(Mpad / 2), dim3(256), 0, stream,
                     Xb, cw, rowStart, Y, N);
  hipLaunchKernelGGL(k_gemm,      dim3(Mtiles * 4), dim3(256), 0, stream, Y, Wt, b, out, N);
}